// Round 2
// baseline (157.450 us; speedup 1.0000x reference)
//
#include <hip/hip_runtime.h>
#include <math.h>

// ---------------------------------------------------------------------------
// Weighted Gaussian-MMD loss (StructuredKernel_79439715107059)
//
// Round 2 structure:
//   0. hipMemsetAsync: zero 9 sum floats + 48 partial floats in ws
//   1. weight_kernel : per-point MLP -> raw softplus weight w; position scaled
//                      by exp(log_scale) AND by u=sqrt(log2e/(2 sigma^2)) so the
//                      pair kernel is exp2(-(dx^2+dy^2)) with NO extra multiply.
//                      Wave-reduced atomics for {sum w, sum w*x, sum w*y} per cloud.
//   2. mmd_kernel    : 3 terms, grid 32x32x3 (12288 waves -> high occupancy).
//                      No LDS: j-point is wave-uniform -> scalar s_load path,
//                      SGPR operands feed VALU directly. Centering is folded:
//                      same-cloud terms need none; cross term subtracts the
//                      mean-offset delta once per i point. Raw (unnormalized)
//                      weights; normalization applied in final_kernel.
//   3. final_kernel  : reduce 48 partials, divide by (sw_b, sw_t) products,
//                      gate MLP, out = loss*gate + bias.
// ---------------------------------------------------------------------------

#define WK_THREADS 256
#define MMD_THREADS 256
#define IB 256   // i-points per block (1 per thread)
#define JB 256   // j-points per block (uniform loop)
#define NPART 16 // partial-accumulator slots per term

__device__ __forceinline__ float softplusf(float x) {
    return fmaxf(x, 0.0f) + log1pf(expf(-fabsf(x)));
}

__device__ __forceinline__ float fast_exp2(float x) {
#if __has_builtin(__builtin_amdgcn_exp2f)
    return __builtin_amdgcn_exp2f(x);
#else
    return exp2f(x);
#endif
}

// ws float layout: sums[0..8]  (0..2 unused legacy, 3..5 base {sw,swx,swy},
//                               6..8 target {sw,swx,swy})
//                  partial[9..56]  (3 terms x NPART slots)
__global__ __launch_bounds__(WK_THREADS) void weight_kernel(
    const float* __restrict__ bpos, const float* __restrict__ bfeat,
    const float* __restrict__ tpos, const float* __restrict__ tfeat,
    const float* __restrict__ w1, const float* __restrict__ b1,
    const float* __restrict__ w2, const float* __restrict__ b2,
    const float* __restrict__ log_sigma, const float* __restrict__ log_scale,
    float4* __restrict__ b4, float4* __restrict__ t4,
    float* __restrict__ sums, int n, int m)
{
    int idx = blockIdx.x * WK_THREADS + threadIdx.x;
    int total = n + m;
    float w = 0.f, px = 0.f, py = 0.f;
    int cloud = 0;
    if (idx < total) {
        const float* pos; const float* feat; int i;
        if (idx < n) { pos = bpos; feat = bfeat; i = idx; cloud = 0; }
        else         { pos = tpos; feat = tfeat; i = idx - n; cloud = 1; }
        float sigma = expf(log_sigma[0]);
        float u = 0.8493218003f / sigma;        // sqrt(log2e/2)/sigma
        float sx = expf(log_scale[0]) * u;
        float sy = expf(log_scale[1]) * u;
        px = pos[2*i]   * sx;
        py = pos[2*i+1] * sy;
        float f0 = feat[5*i], f1 = feat[5*i+1], f2 = feat[5*i+2],
              f3 = feat[5*i+3], f4 = feat[5*i+4];
        float logit = b2[0];
        #pragma unroll
        for (int h = 0; h < 32; ++h) {
            float a = b1[h];
            a = fmaf(f0, w1[h],      a);
            a = fmaf(f1, w1[32+h],   a);
            a = fmaf(f2, w1[64+h],   a);
            a = fmaf(f3, w1[96+h],   a);
            a = fmaf(f4, w1[128+h],  a);
            a = fmaxf(a, 0.f);
            logit = fmaf(a, w2[h], logit);
        }
        w = softplusf(logit) + 1e-6f;
        float4 v = make_float4(px, py, w, 0.f);
        if (cloud == 0) b4[i] = v; else t4[i] = v;
    }
    // n,m multiples of 64 -> cloud is wave-uniform
    float sw = w, swx = w*px, swy = w*py;
    #pragma unroll
    for (int off = 32; off > 0; off >>= 1) {
        sw  += __shfl_down(sw,  off, 64);
        swx += __shfl_down(swx, off, 64);
        swy += __shfl_down(swy, off, 64);
    }
    if ((threadIdx.x & 63) == 0 && idx < total) {
        float* dst = sums + 3 + cloud * 3;
        atomicAdd(dst + 0, sw);
        atomicAdd(dst + 1, swx);
        atomicAdd(dst + 2, swy);
    }
}

__global__ __launch_bounds__(MMD_THREADS) void mmd_kernel(
    const float4* __restrict__ b4, const float4* __restrict__ t4,
    const float* __restrict__ sums, float* __restrict__ partial,
    int n, int m)
{
    int t = blockIdx.z;
    const float4* X; const float4* Y; int nx, ny;
    if (t == 0)      { X = b4; Y = b4; nx = n; ny = n; }
    else if (t == 1) { X = b4; Y = t4; nx = n; ny = m; }
    else             { X = t4; Y = t4; nx = m; ny = m; }

    int ibase = blockIdx.x * IB;
    int j0 = blockIdx.y * JB;
    if (ibase >= nx || j0 >= ny) return;   // uniform early-out

    // cross-term mean offset (same-cloud centering cancels in differences)
    float dx0 = 0.f, dy0 = 0.f;
    if (t == 1) {
        float sb = sums[3], st = sums[6];
        dx0 = sums[4] / sb - sums[7] / st;
        dy0 = sums[5] / sb - sums[8] / st;
    }

    int i = ibase + threadIdx.x;
    float xi = 0.f, yi = 0.f, wi = 0.f;
    if (i < nx) {
        float4 v = X[i];
        xi = v.x - dx0; yi = v.y - dy0; wi = v.z;
    }

    int jn = min(JB, ny - j0);
    const float4* Yp = Y + j0;          // uniform base -> scalar loads
    float acc = 0.f;
    for (int j = 0; j < jn; ++j) {
        float4 q = Yp[j];               // wave-uniform: s_load_dwordx4
        float dx = xi - q.x;
        float dy = yi - q.y;
        float e = fast_exp2(fmaf(dy, -dy, -(dx * dx)));  // = exp(-d2/(2s^2))
        acc = fmaf(q.z, e, acc);
    }
    float r = wi * acc;

    #pragma unroll
    for (int off = 32; off > 0; off >>= 1) r += __shfl_down(r, off, 64);
    __shared__ float wsum[MMD_THREADS / 64];
    int wid = threadIdx.x >> 6;
    if ((threadIdx.x & 63) == 0) wsum[wid] = r;
    __syncthreads();
    if (threadIdx.x == 0) {
        float tot = 0.f;
        #pragma unroll
        for (int k = 0; k < MMD_THREADS / 64; ++k) tot += wsum[k];
        atomicAdd(&partial[t * NPART + (blockIdx.x & (NPART - 1))], tot);
    }
}

__global__ void final_kernel(
    const float* __restrict__ bdesc, const float* __restrict__ tdesc,
    const float* __restrict__ g1, const float* __restrict__ gb1,
    const float* __restrict__ g2, const float* __restrict__ gb2,
    const float* __restrict__ bias, const float* __restrict__ sums,
    const float* __restrict__ partial, float* __restrict__ out)
{
    if (threadIdx.x != 0 || blockIdx.x != 0) return;
    float P[3];
    #pragma unroll
    for (int t = 0; t < 3; ++t) {
        float s = 0.f;
        #pragma unroll
        for (int k = 0; k < NPART; ++k) s += partial[t * NPART + k];
        P[t] = s;
    }
    float sb = sums[3], st = sums[6];
    float loss = P[0] / (sb * sb) - 2.f * P[1] / (sb * st) + P[2] / (st * st);

    float d0 = fabsf(bdesc[0] - tdesc[0]);
    float d1 = fabsf(bdesc[1] - tdesc[1]);
    float d2 = fabsf(bdesc[2] - tdesc[2]);
    float d3 = fabsf(bdesc[3] - tdesc[3]);
    float logit = gb2[0];
    #pragma unroll
    for (int h = 0; h < 32; ++h) {
        float a = gb1[h];
        a = fmaf(d0, g1[h],      a);
        a = fmaf(d1, g1[32+h],   a);
        a = fmaf(d2, g1[64+h],   a);
        a = fmaf(d3, g1[96+h],   a);
        a = fmaxf(a, 0.f);
        logit = fmaf(a, g2[h], logit);
    }
    float gate = softplusf(logit) + 1e-6f;
    out[0] = loss * gate + bias[0];
}

extern "C" void kernel_launch(void* const* d_in, const int* in_sizes, int n_in,
                              void* d_out, int out_size, void* d_ws, size_t ws_size,
                              hipStream_t stream)
{
    const float* bpos      = (const float*)d_in[0];
    const float* bfeat     = (const float*)d_in[1];
    const float* bdesc     = (const float*)d_in[2];
    const float* tpos      = (const float*)d_in[3];
    const float* tfeat     = (const float*)d_in[4];
    const float* tdesc     = (const float*)d_in[5];
    const float* w1        = (const float*)d_in[6];
    const float* b1        = (const float*)d_in[7];
    const float* w2        = (const float*)d_in[8];
    const float* b2        = (const float*)d_in[9];
    const float* g1        = (const float*)d_in[10];
    const float* gb1       = (const float*)d_in[11];
    const float* g2        = (const float*)d_in[12];
    const float* gb2       = (const float*)d_in[13];
    const float* log_sigma = (const float*)d_in[14];
    const float* log_scale = (const float*)d_in[15];
    const float* bias      = (const float*)d_in[16];
    float* out = (float*)d_out;

    int n = in_sizes[0] / 2;   // 8192
    int m = in_sizes[3] / 2;   // 8192

    char* ws = (char*)d_ws;
    float4* b4   = (float4*)ws;
    float4* t4   = (float4*)(ws + (size_t)n * sizeof(float4));
    float* sums  = (float*)(ws + (size_t)(n + m) * sizeof(float4));  // 9 floats
    float* partial = sums + 9;                                       // 48 floats

    hipMemsetAsync(sums, 0, (9 + 3 * NPART) * sizeof(float), stream);

    int total = n + m;
    int wb = (total + WK_THREADS - 1) / WK_THREADS;
    weight_kernel<<<wb, WK_THREADS, 0, stream>>>(
        bpos, bfeat, tpos, tfeat, w1, b1, w2, b2, log_sigma, log_scale,
        b4, t4, sums, n, m);

    int nmax = n > m ? n : m;
    dim3 grid((nmax + IB - 1) / IB, (nmax + JB - 1) / JB, 3);
    mmd_kernel<<<grid, MMD_THREADS, 0, stream>>>(b4, t4, sums, partial, n, m);

    final_kernel<<<1, 64, 0, stream>>>(bdesc, tdesc, g1, gb1, g2, gb2,
                                       bias, sums, partial, out);
}

// Round 3
// 126.508 us; speedup vs baseline: 1.2446x; 1.2446x over previous
//
#include <hip/hip_runtime.h>
#include <math.h>

// ---------------------------------------------------------------------------
// Weighted Gaussian-MMD loss — round 3
//
//   1. weight_kernel : MLP weights staged in LDS; per-point softplus weight w,
//                      coords pre-scaled by exp(log_scale)*sqrt(log2e)/(sqrt2*sigma),
//                      h = -(x^2+y^2); float4 {x,y,h,w}. Per-WAVE partial sums
//                      {sw,swx,swy} per cloud written to DISTINCT slots (no
//                      atomics, no memset needed).
//   2. mmd_kernel    : 3 terms, grid (8,64,3)=1536 blocks (75% occupancy).
//                      LDS j-tile (128 float4, broadcast ds_read_b128),
//                      I_PT=4 i-points/thread. Dot form:
//                      exponent = h_i + h_j + 2*x_i.x_j  (== -(d2 scaled), <=0)
//                      -> add, fma, fma, exp2, fma per pair.
//                      Cross term (t=1) shifts i-points by the mean offset
//                      (same-cloud centering cancels). Per-block result to
//                      distinct partial slot.
//   3. final_kernel  : reduce wave partials + block partials, normalize by
//                      (sum w)^2 products, gate MLP (32-lane parallel),
//                      out = loss*gate + bias.
// ---------------------------------------------------------------------------

#define WK_THREADS 256
#define MMD_THREADS 256
#define I_PT 4
#define IB (MMD_THREADS * I_PT)   // 1024 i-points per block
#define JB 128                    // j-points per block (LDS tile)

__device__ __forceinline__ float softplusf(float x) {
    return fmaxf(x, 0.0f) + log1pf(expf(-fabsf(x)));
}

__device__ __forceinline__ float fast_exp2(float x) {
#if __has_builtin(__builtin_amdgcn_exp2f)
    return __builtin_amdgcn_exp2f(x);
#else
    return exp2f(x);
#endif
}

// wpart slot layout (per wave): {sw_b, swx_b, swy_b, sw_t, swx_t, swy_t}
__global__ __launch_bounds__(WK_THREADS) void weight_kernel(
    const float* __restrict__ bpos, const float* __restrict__ bfeat,
    const float* __restrict__ tpos, const float* __restrict__ tfeat,
    const float* __restrict__ w1, const float* __restrict__ b1,
    const float* __restrict__ w2, const float* __restrict__ b2,
    const float* __restrict__ log_sigma, const float* __restrict__ log_scale,
    float4* __restrict__ b4, float4* __restrict__ t4,
    float* __restrict__ wpart, int n, int m)
{
    __shared__ float s_w1[160], s_b1[32], s_w2[32];
    int tid = threadIdx.x;
    if (tid < 160) s_w1[tid] = w1[tid];
    if (tid < 32) { s_b1[tid] = b1[tid]; s_w2[tid] = w2[tid]; }
    __syncthreads();

    int idx = blockIdx.x * WK_THREADS + tid;
    int total = n + m;
    float w = 0.f, px = 0.f, py = 0.f;
    int cloud = 0;
    if (idx < total) {
        const float* pos; const float* feat; int i;
        if (idx < n) { pos = bpos; feat = bfeat; i = idx; cloud = 0; }
        else         { pos = tpos; feat = tfeat; i = idx - n; cloud = 1; }
        float sigma = expf(log_sigma[0]);
        float u = 0.8493218003f / sigma;          // sqrt(log2e/2)/sigma
        float sx = expf(log_scale[0]) * u;
        float sy = expf(log_scale[1]) * u;
        px = pos[2*i]   * sx;
        py = pos[2*i+1] * sy;
        float f0 = feat[5*i], f1 = feat[5*i+1], f2 = feat[5*i+2],
              f3 = feat[5*i+3], f4 = feat[5*i+4];
        float logit = b2[0];
        #pragma unroll
        for (int h = 0; h < 32; ++h) {
            float a = s_b1[h];
            a = fmaf(f0, s_w1[h],      a);
            a = fmaf(f1, s_w1[32+h],   a);
            a = fmaf(f2, s_w1[64+h],   a);
            a = fmaf(f3, s_w1[96+h],   a);
            a = fmaf(f4, s_w1[128+h],  a);
            a = fmaxf(a, 0.f);
            logit = fmaf(a, s_w2[h], logit);
        }
        w = softplusf(logit) + 1e-6f;
        float h_i = -fmaf(px, px, py * py);
        float4 v = make_float4(px, py, h_i, w);
        if (cloud == 0) b4[i] = v; else t4[i] = v;
    }
    // n,m multiples of 64 -> cloud is wave-uniform
    float sw = w, swx = w * px, swy = w * py;
    #pragma unroll
    for (int off = 32; off > 0; off >>= 1) {
        sw  += __shfl_down(sw,  off, 64);
        swx += __shfl_down(swx, off, 64);
        swy += __shfl_down(swy, off, 64);
    }
    if ((tid & 63) == 0) {
        int wgid = blockIdx.x * (WK_THREADS / 64) + (tid >> 6);
        float* dst = wpart + wgid * 6;
        bool valid = (idx < total);
        float z = valid ? 1.f : 0.f;
        if (cloud == 0) {
            dst[0] = sw * z; dst[1] = swx * z; dst[2] = swy * z;
            dst[3] = 0.f;    dst[4] = 0.f;     dst[5] = 0.f;
        } else {
            dst[0] = 0.f;    dst[1] = 0.f;     dst[2] = 0.f;
            dst[3] = sw * z; dst[4] = swx * z; dst[5] = swy * z;
        }
    }
}

// block-wide reduction of wpart[nslots][6] -> out[6] (same value on all threads)
__device__ __forceinline__ void reduce_wpart(const float* __restrict__ wpart,
                                             int nslots, float out[6])
{
    __shared__ float lds6[4][6];
    float v[6];
    #pragma unroll
    for (int k = 0; k < 6; ++k) v[k] = 0.f;
    for (int s = threadIdx.x; s < nslots; s += blockDim.x) {
        #pragma unroll
        for (int k = 0; k < 6; ++k) v[k] += wpart[s * 6 + k];
    }
    #pragma unroll
    for (int off = 32; off > 0; off >>= 1) {
        #pragma unroll
        for (int k = 0; k < 6; ++k) v[k] += __shfl_down(v[k], off, 64);
    }
    if ((threadIdx.x & 63) == 0) {
        #pragma unroll
        for (int k = 0; k < 6; ++k) lds6[threadIdx.x >> 6][k] = v[k];
    }
    __syncthreads();
    #pragma unroll
    for (int k = 0; k < 6; ++k)
        out[k] = lds6[0][k] + lds6[1][k] + lds6[2][k] + lds6[3][k];
    __syncthreads();
}

__global__ __launch_bounds__(MMD_THREADS) void mmd_kernel(
    const float4* __restrict__ b4, const float4* __restrict__ t4,
    const float* __restrict__ wpart, int nwslots,
    float* __restrict__ partial, int n, int m, int gx, int gy)
{
    int t = blockIdx.z;
    const float4* X; const float4* Y; int nx, ny;
    if (t == 0)      { X = b4; Y = b4; nx = n; ny = n; }
    else if (t == 1) { X = b4; Y = t4; nx = n; ny = m; }
    else             { X = t4; Y = t4; nx = m; ny = m; }

    int slot = (t * gy + blockIdx.y) * gx + blockIdx.x;
    int ibase = blockIdx.x * IB;
    int j0 = blockIdx.y * JB;
    if (ibase >= nx || j0 >= ny) {            // uniform; must still fill slot
        if (threadIdx.x == 0) partial[slot] = 0.f;
        return;
    }

    float dx0 = 0.f, dy0 = 0.f;
    if (t == 1) {   // cross term: shift i-points by mean offset
        float o[6];
        reduce_wpart(wpart, nwslots, o);
        dx0 = o[1] / o[0] - o[4] / o[3];
        dy0 = o[2] / o[0] - o[5] / o[3];
    }

    __shared__ float4 ytile[JB];
    if (threadIdx.x < JB) {
        int jj = j0 + threadIdx.x;
        ytile[threadIdx.x] = (jj < ny) ? Y[jj] : make_float4(0.f, 0.f, 0.f, 0.f);
    }
    __syncthreads();

    float x2[I_PT], y2[I_PT], hi_[I_PT], wi[I_PT], acc[I_PT];
    #pragma unroll
    for (int s = 0; s < I_PT; ++s) {
        int ii = ibase + s * MMD_THREADS + threadIdx.x;
        float4 v = (ii < nx) ? X[ii] : make_float4(0.f, 0.f, 0.f, 0.f);
        float xc = v.x - dx0, yc = v.y - dy0;
        x2[s] = xc + xc;
        y2[s] = yc + yc;
        hi_[s] = -fmaf(xc, xc, yc * yc);
        wi[s] = v.w;
        acc[s] = 0.f;
    }

    int jn = min(JB, ny - j0);
    #pragma unroll 2
    for (int j = 0; j < jn; ++j) {
        float4 q = ytile[j];                  // broadcast ds_read_b128
        #pragma unroll
        for (int s = 0; s < I_PT; ++s) {
            float u = hi_[s] + q.z;           // h_i + h_j
            u = fmaf(x2[s], q.x, u);
            u = fmaf(y2[s], q.y, u);          // = -(dx^2+dy^2) in scaled units
            acc[s] = fmaf(q.w, fast_exp2(u), acc[s]);
        }
    }
    float r = 0.f;
    #pragma unroll
    for (int s = 0; s < I_PT; ++s) r = fmaf(wi[s], acc[s], r);

    #pragma unroll
    for (int off = 32; off > 0; off >>= 1) r += __shfl_down(r, off, 64);
    __shared__ float wsum[MMD_THREADS / 64];
    if ((threadIdx.x & 63) == 0) wsum[threadIdx.x >> 6] = r;
    __syncthreads();
    if (threadIdx.x == 0) {
        float tot = 0.f;
        #pragma unroll
        for (int k = 0; k < MMD_THREADS / 64; ++k) tot += wsum[k];
        partial[slot] = tot;                  // distinct slot, no atomics
    }
}

__global__ __launch_bounds__(256) void final_kernel(
    const float* __restrict__ bdesc, const float* __restrict__ tdesc,
    const float* __restrict__ g1, const float* __restrict__ gb1,
    const float* __restrict__ g2, const float* __restrict__ gb2,
    const float* __restrict__ bias, const float* __restrict__ wpart, int nwslots,
    const float* __restrict__ partial, int gx, int gy,
    float* __restrict__ out)
{
    float o[6];
    reduce_wpart(wpart, nwslots, o);
    float sb = o[0], st = o[3];

    int np1 = gx * gy;
    float p0 = 0.f, p1 = 0.f, p2 = 0.f;
    for (int k = threadIdx.x; k < 3 * np1; k += 256) {
        float v = partial[k];
        int term = k / np1;
        if (term == 0) p0 += v; else if (term == 1) p1 += v; else p2 += v;
    }
    #pragma unroll
    for (int off = 32; off > 0; off >>= 1) {
        p0 += __shfl_down(p0, off, 64);
        p1 += __shfl_down(p1, off, 64);
        p2 += __shfl_down(p2, off, 64);
    }
    __shared__ float lds3[4][3];
    if ((threadIdx.x & 63) == 0) {
        lds3[threadIdx.x >> 6][0] = p0;
        lds3[threadIdx.x >> 6][1] = p1;
        lds3[threadIdx.x >> 6][2] = p2;
    }
    __syncthreads();
    float P0 = lds3[0][0] + lds3[1][0] + lds3[2][0] + lds3[3][0];
    float P1 = lds3[0][1] + lds3[1][1] + lds3[2][1] + lds3[3][1];
    float P2 = lds3[0][2] + lds3[1][2] + lds3[2][2] + lds3[3][2];

    // gate MLP: 32 lanes each compute one hidden unit, reduce
    float a = 0.f;
    if (threadIdx.x < 32) {
        int h = threadIdx.x;
        float d0 = fabsf(bdesc[0] - tdesc[0]);
        float d1 = fabsf(bdesc[1] - tdesc[1]);
        float d2 = fabsf(bdesc[2] - tdesc[2]);
        float d3 = fabsf(bdesc[3] - tdesc[3]);
        float v = gb1[h];
        v = fmaf(d0, g1[h],      v);
        v = fmaf(d1, g1[32+h],   v);
        v = fmaf(d2, g1[64+h],   v);
        v = fmaf(d3, g1[96+h],   v);
        a = fmaxf(v, 0.f) * g2[h];
    }
    #pragma unroll
    for (int off = 16; off > 0; off >>= 1) a += __shfl_down(a, off, 64);
    if (threadIdx.x == 0) {
        float gate = softplusf(a + gb2[0]) + 1e-6f;
        float loss = P0 / (sb * sb) - 2.f * P1 / (sb * st) + P2 / (st * st);
        out[0] = loss * gate + bias[0];
    }
}

extern "C" void kernel_launch(void* const* d_in, const int* in_sizes, int n_in,
                              void* d_out, int out_size, void* d_ws, size_t ws_size,
                              hipStream_t stream)
{
    const float* bpos      = (const float*)d_in[0];
    const float* bfeat     = (const float*)d_in[1];
    const float* bdesc     = (const float*)d_in[2];
    const float* tpos      = (const float*)d_in[3];
    const float* tfeat     = (const float*)d_in[4];
    const float* tdesc     = (const float*)d_in[5];
    const float* w1        = (const float*)d_in[6];
    const float* b1        = (const float*)d_in[7];
    const float* w2        = (const float*)d_in[8];
    const float* b2        = (const float*)d_in[9];
    const float* g1        = (const float*)d_in[10];
    const float* gb1       = (const float*)d_in[11];
    const float* g2        = (const float*)d_in[12];
    const float* gb2       = (const float*)d_in[13];
    const float* log_sigma = (const float*)d_in[14];
    const float* log_scale = (const float*)d_in[15];
    const float* bias      = (const float*)d_in[16];
    float* out = (float*)d_out;

    int n = in_sizes[0] / 2;   // 8192
    int m = in_sizes[3] / 2;   // 8192

    int wb = (n + m + WK_THREADS - 1) / WK_THREADS;      // 64 blocks
    int nwslots = wb * (WK_THREADS / 64);                // 256 wave slots
    int nmax = n > m ? n : m;
    int gx = (nmax + IB - 1) / IB;                       // 8
    int gy = (nmax + JB - 1) / JB;                       // 64

    char* ws = (char*)d_ws;
    float4* b4    = (float4*)ws;
    float4* t4    = (float4*)(ws + (size_t)n * sizeof(float4));
    float* wpart  = (float*)(ws + (size_t)(n + m) * sizeof(float4));
    float* partial = wpart + (size_t)nwslots * 6;

    weight_kernel<<<wb, WK_THREADS, 0, stream>>>(
        bpos, bfeat, tpos, tfeat, w1, b1, w2, b2, log_sigma, log_scale,
        b4, t4, wpart, n, m);

    dim3 grid(gx, gy, 3);
    mmd_kernel<<<grid, MMD_THREADS, 0, stream>>>(
        b4, t4, wpart, nwslots, partial, n, m, gx, gy);

    final_kernel<<<1, 256, 0, stream>>>(
        bdesc, tdesc, g1, gb1, g2, gb2, bias, wpart, nwslots,
        partial, gx, gy, out);
}

// Round 4
// 124.598 us; speedup vs baseline: 1.2637x; 1.0153x over previous
//
#include <hip/hip_runtime.h>
#include <math.h>

// ---------------------------------------------------------------------------
// Weighted Gaussian-MMD loss — round 4
//
//   1. weight_kernel : MLP weights in LDS; per-point softplus weight w, coords
//                      pre-scaled by exp(log_scale)*sqrt(log2e/2)/sigma,
//                      h = -(x^2+y^2); float4 {x,y,h,w}. Per-wave partials
//                      {sw,swx,swy,sw2} per cloud to distinct slots (no atomics).
//   2. mmd_kernel    : 3 terms. Same-cloud terms (t=0,2) use SYMMETRY:
//                      only tiles with j0 >= ibase run; diagonal-band tiles
//                      (j0 < ibase+IB) predicate jj > ii; term = 2*P + sum(w^2).
//                      Cross term (t=1) full grid, i-points shifted by the
//                      weighted-mean offset (same-cloud centering cancels).
//                      Inner pair: exponent = h_i + h_j + 2*x_i.x_j  (<= 0)
//                      -> add, fma, fma, exp2, fma. LDS j-tile broadcast reads.
//   3. final_kernel  : reduce wave/block partials, normalize by (sum w)
//                      products, gate MLP, out = loss*gate + bias.
// ---------------------------------------------------------------------------

#define WK_THREADS 256
#define MMD_THREADS 256
#define I_PT 4
#define IB (MMD_THREADS * I_PT)   // 1024 i-points per block
#define JB 128                    // j-points per block (LDS tile)

__device__ __forceinline__ float softplusf(float x) {
    return fmaxf(x, 0.0f) + log1pf(expf(-fabsf(x)));
}

__device__ __forceinline__ float fast_exp2(float x) {
#if __has_builtin(__builtin_amdgcn_exp2f)
    return __builtin_amdgcn_exp2f(x);
#else
    return exp2f(x);
#endif
}

// wpart slot layout (8 floats per wave):
//   {sw_b, swx_b, swy_b, sw2_b, sw_t, swx_t, swy_t, sw2_t}
__global__ __launch_bounds__(WK_THREADS) void weight_kernel(
    const float* __restrict__ bpos, const float* __restrict__ bfeat,
    const float* __restrict__ tpos, const float* __restrict__ tfeat,
    const float* __restrict__ w1, const float* __restrict__ b1,
    const float* __restrict__ w2, const float* __restrict__ b2,
    const float* __restrict__ log_sigma, const float* __restrict__ log_scale,
    float4* __restrict__ b4, float4* __restrict__ t4,
    float* __restrict__ wpart, int n, int m)
{
    __shared__ float s_w1[160], s_b1[32], s_w2[32];
    int tid = threadIdx.x;
    if (tid < 160) s_w1[tid] = w1[tid];
    if (tid < 32) { s_b1[tid] = b1[tid]; s_w2[tid] = w2[tid]; }
    __syncthreads();

    int idx = blockIdx.x * WK_THREADS + tid;
    int total = n + m;
    float w = 0.f, px = 0.f, py = 0.f;
    int cloud = 0;
    if (idx < total) {
        const float* pos; const float* feat; int i;
        if (idx < n) { pos = bpos; feat = bfeat; i = idx; cloud = 0; }
        else         { pos = tpos; feat = tfeat; i = idx - n; cloud = 1; }
        float sigma = expf(log_sigma[0]);
        float u = 0.8493218003f / sigma;          // sqrt(log2e/2)/sigma
        float sx = expf(log_scale[0]) * u;
        float sy = expf(log_scale[1]) * u;
        px = pos[2*i]   * sx;
        py = pos[2*i+1] * sy;
        float f0 = feat[5*i], f1 = feat[5*i+1], f2 = feat[5*i+2],
              f3 = feat[5*i+3], f4 = feat[5*i+4];
        float logit = b2[0];
        #pragma unroll
        for (int h = 0; h < 32; ++h) {
            float a = s_b1[h];
            a = fmaf(f0, s_w1[h],      a);
            a = fmaf(f1, s_w1[32+h],   a);
            a = fmaf(f2, s_w1[64+h],   a);
            a = fmaf(f3, s_w1[96+h],   a);
            a = fmaf(f4, s_w1[128+h],  a);
            a = fmaxf(a, 0.f);
            logit = fmaf(a, s_w2[h], logit);
        }
        w = softplusf(logit) + 1e-6f;
        float h_i = -fmaf(px, px, py * py);
        float4 v = make_float4(px, py, h_i, w);
        if (cloud == 0) b4[i] = v; else t4[i] = v;
    }
    // n,m multiples of 64 -> cloud is wave-uniform
    float sw = w, swx = w * px, swy = w * py, sw2 = w * w;
    #pragma unroll
    for (int off = 32; off > 0; off >>= 1) {
        sw  += __shfl_down(sw,  off, 64);
        swx += __shfl_down(swx, off, 64);
        swy += __shfl_down(swy, off, 64);
        sw2 += __shfl_down(sw2, off, 64);
    }
    if ((tid & 63) == 0) {
        int wgid = blockIdx.x * (WK_THREADS / 64) + (tid >> 6);
        float* dst = wpart + wgid * 8;
        float z = (idx < total) ? 1.f : 0.f;
        if (cloud == 0) {
            dst[0] = sw * z; dst[1] = swx * z; dst[2] = swy * z; dst[3] = sw2 * z;
            dst[4] = 0.f;    dst[5] = 0.f;     dst[6] = 0.f;     dst[7] = 0.f;
        } else {
            dst[0] = 0.f;    dst[1] = 0.f;     dst[2] = 0.f;     dst[3] = 0.f;
            dst[4] = sw * z; dst[5] = swx * z; dst[6] = swy * z; dst[7] = sw2 * z;
        }
    }
}

// block-wide reduction of wpart[nslots][8] -> out[8] (same value on all threads)
__device__ __forceinline__ void reduce_wpart(const float* __restrict__ wpart,
                                             int nslots, float out[8])
{
    __shared__ float lds8[4][8];
    float v[8];
    #pragma unroll
    for (int k = 0; k < 8; ++k) v[k] = 0.f;
    for (int s = threadIdx.x; s < nslots; s += blockDim.x) {
        #pragma unroll
        for (int k = 0; k < 8; ++k) v[k] += wpart[s * 8 + k];
    }
    #pragma unroll
    for (int off = 32; off > 0; off >>= 1) {
        #pragma unroll
        for (int k = 0; k < 8; ++k) v[k] += __shfl_down(v[k], off, 64);
    }
    if ((threadIdx.x & 63) == 0) {
        #pragma unroll
        for (int k = 0; k < 8; ++k) lds8[threadIdx.x >> 6][k] = v[k];
    }
    __syncthreads();
    #pragma unroll
    for (int k = 0; k < 8; ++k)
        out[k] = lds8[0][k] + lds8[1][k] + lds8[2][k] + lds8[3][k];
    __syncthreads();
}

__global__ __launch_bounds__(MMD_THREADS) void mmd_kernel(
    const float4* __restrict__ b4, const float4* __restrict__ t4,
    const float* __restrict__ wpart, int nwslots,
    float* __restrict__ partial, int n, int m, int gx, int gy)
{
    int t = blockIdx.z;
    const float4* X; const float4* Y; int nx, ny;
    if (t == 0)      { X = b4; Y = b4; nx = n; ny = n; }
    else if (t == 1) { X = b4; Y = t4; nx = n; ny = m; }
    else             { X = t4; Y = t4; nx = m; ny = m; }

    int slot = (t * gy + blockIdx.y) * gx + blockIdx.x;
    int ibase = blockIdx.x * IB;
    int j0 = blockIdx.y * JB;
    bool same = (t != 1);
    // symmetric terms: skip tiles strictly below the diagonal (j0 < ibase)
    if (ibase >= nx || j0 >= ny || (same && j0 < ibase)) {
        if (threadIdx.x == 0) partial[slot] = 0.f;   // ws is poisoned; must write
        return;
    }

    float dx0 = 0.f, dy0 = 0.f;
    if (t == 1) {   // cross term: shift i-points by mean offset
        float o[8];
        reduce_wpart(wpart, nwslots, o);
        dx0 = o[1] / o[0] - o[5] / o[4];
        dy0 = o[2] / o[0] - o[6] / o[4];
    }

    __shared__ float4 ytile[JB];
    if (threadIdx.x < JB) {
        int jj = j0 + threadIdx.x;
        ytile[threadIdx.x] = (jj < ny) ? Y[jj] : make_float4(0.f, 0.f, 0.f, 0.f);
    }
    __syncthreads();

    float x2[I_PT], y2[I_PT], hi_[I_PT], wi[I_PT], acc[I_PT];
    int ii_[I_PT];
    #pragma unroll
    for (int s = 0; s < I_PT; ++s) {
        int ii = ibase + s * MMD_THREADS + threadIdx.x;
        ii_[s] = ii;
        float4 v = (ii < nx) ? X[ii] : make_float4(0.f, 0.f, 0.f, 0.f);
        float xc = v.x - dx0, yc = v.y - dy0;
        x2[s] = xc + xc;
        y2[s] = yc + yc;
        hi_[s] = -fmaf(xc, xc, yc * yc);
        wi[s] = v.w;
        acc[s] = 0.f;
    }

    int jn = min(JB, ny - j0);
    if (same && j0 < ibase + IB) {
        // diagonal-band tile: count only strict upper triangle (jj > ii)
        #pragma unroll 2
        for (int j = 0; j < jn; ++j) {
            float4 q = ytile[j];
            int jj = j0 + j;
            #pragma unroll
            for (int s = 0; s < I_PT; ++s) {
                float u = hi_[s] + q.z;
                u = fmaf(x2[s], q.x, u);
                u = fmaf(y2[s], q.y, u);
                float e = fast_exp2(u);
                float qw = (jj > ii_[s]) ? q.w : 0.f;
                acc[s] = fmaf(qw, e, acc[s]);
            }
        }
    } else {
        #pragma unroll 2
        for (int j = 0; j < jn; ++j) {
            float4 q = ytile[j];
            #pragma unroll
            for (int s = 0; s < I_PT; ++s) {
                float u = hi_[s] + q.z;
                u = fmaf(x2[s], q.x, u);
                u = fmaf(y2[s], q.y, u);
                acc[s] = fmaf(q.w, fast_exp2(u), acc[s]);
            }
        }
    }
    float r = 0.f;
    #pragma unroll
    for (int s = 0; s < I_PT; ++s) r = fmaf(wi[s], acc[s], r);

    #pragma unroll
    for (int off = 32; off > 0; off >>= 1) r += __shfl_down(r, off, 64);
    __shared__ float wsum[MMD_THREADS / 64];
    if ((threadIdx.x & 63) == 0) wsum[threadIdx.x >> 6] = r;
    __syncthreads();
    if (threadIdx.x == 0) {
        float tot = 0.f;
        #pragma unroll
        for (int k = 0; k < MMD_THREADS / 64; ++k) tot += wsum[k];
        partial[slot] = tot;                  // distinct slot, no atomics
    }
}

__global__ __launch_bounds__(256) void final_kernel(
    const float* __restrict__ bdesc, const float* __restrict__ tdesc,
    const float* __restrict__ g1, const float* __restrict__ gb1,
    const float* __restrict__ g2, const float* __restrict__ gb2,
    const float* __restrict__ bias, const float* __restrict__ wpart, int nwslots,
    const float* __restrict__ partial, int gx, int gy,
    float* __restrict__ out)
{
    float o[8];
    reduce_wpart(wpart, nwslots, o);
    float sb = o[0], st = o[4];
    float sw2b = o[3], sw2t = o[7];

    int np1 = gx * gy;
    float p0 = 0.f, p1 = 0.f, p2 = 0.f;
    for (int k = threadIdx.x; k < 3 * np1; k += 256) {
        float v = partial[k];
        int term = k / np1;
        if (term == 0) p0 += v; else if (term == 1) p1 += v; else p2 += v;
    }
    #pragma unroll
    for (int off = 32; off > 0; off >>= 1) {
        p0 += __shfl_down(p0, off, 64);
        p1 += __shfl_down(p1, off, 64);
        p2 += __shfl_down(p2, off, 64);
    }
    __shared__ float lds3[4][3];
    if ((threadIdx.x & 63) == 0) {
        lds3[threadIdx.x >> 6][0] = p0;
        lds3[threadIdx.x >> 6][1] = p1;
        lds3[threadIdx.x >> 6][2] = p2;
    }
    __syncthreads();
    float P0 = lds3[0][0] + lds3[1][0] + lds3[2][0] + lds3[3][0];
    float P1 = lds3[0][1] + lds3[1][1] + lds3[2][1] + lds3[3][1];
    float P2 = lds3[0][2] + lds3[1][2] + lds3[2][2] + lds3[3][2];

    // symmetric terms: full sum = 2*upper + diagonal(sum w^2)
    float T0 = 2.f * P0 + sw2b;
    float T2 = 2.f * P2 + sw2t;

    // gate MLP: 32 lanes each compute one hidden unit, reduce
    float a = 0.f;
    if (threadIdx.x < 32) {
        int h = threadIdx.x;
        float d0 = fabsf(bdesc[0] - tdesc[0]);
        float d1 = fabsf(bdesc[1] - tdesc[1]);
        float d2 = fabsf(bdesc[2] - tdesc[2]);
        float d3 = fabsf(bdesc[3] - tdesc[3]);
        float v = gb1[h];
        v = fmaf(d0, g1[h],      v);
        v = fmaf(d1, g1[32+h],   v);
        v = fmaf(d2, g1[64+h],   v);
        v = fmaf(d3, g1[96+h],   v);
        a = fmaxf(v, 0.f) * g2[h];
    }
    #pragma unroll
    for (int off = 16; off > 0; off >>= 1) a += __shfl_down(a, off, 64);
    if (threadIdx.x == 0) {
        float gate = softplusf(a + gb2[0]) + 1e-6f;
        float loss = T0 / (sb * sb) - 2.f * P1 / (sb * st) + T2 / (st * st);
        out[0] = loss * gate + bias[0];
    }
}

extern "C" void kernel_launch(void* const* d_in, const int* in_sizes, int n_in,
                              void* d_out, int out_size, void* d_ws, size_t ws_size,
                              hipStream_t stream)
{
    const float* bpos      = (const float*)d_in[0];
    const float* bfeat     = (const float*)d_in[1];
    const float* bdesc     = (const float*)d_in[2];
    const float* tpos      = (const float*)d_in[3];
    const float* tfeat     = (const float*)d_in[4];
    const float* tdesc     = (const float*)d_in[5];
    const float* w1        = (const float*)d_in[6];
    const float* b1        = (const float*)d_in[7];
    const float* w2        = (const float*)d_in[8];
    const float* b2        = (const float*)d_in[9];
    const float* g1        = (const float*)d_in[10];
    const float* gb1       = (const float*)d_in[11];
    const float* g2        = (const float*)d_in[12];
    const float* gb2       = (const float*)d_in[13];
    const float* log_sigma = (const float*)d_in[14];
    const float* log_scale = (const float*)d_in[15];
    const float* bias      = (const float*)d_in[16];
    float* out = (float*)d_out;

    int n = in_sizes[0] / 2;   // 8192
    int m = in_sizes[3] / 2;   // 8192

    int wb = (n + m + WK_THREADS - 1) / WK_THREADS;      // 64 blocks
    int nwslots = wb * (WK_THREADS / 64);                // 256 wave slots
    int nmax = n > m ? n : m;
    int gx = (nmax + IB - 1) / IB;                       // 8
    int gy = (nmax + JB - 1) / JB;                       // 64

    char* ws = (char*)d_ws;
    float4* b4    = (float4*)ws;
    float4* t4    = (float4*)(ws + (size_t)n * sizeof(float4));
    float* wpart  = (float*)(ws + (size_t)(n + m) * sizeof(float4));
    float* partial = wpart + (size_t)nwslots * 8;

    weight_kernel<<<wb, WK_THREADS, 0, stream>>>(
        bpos, bfeat, tpos, tfeat, w1, b1, w2, b2, log_sigma, log_scale,
        b4, t4, wpart, n, m);

    dim3 grid(gx, gy, 3);
    mmd_kernel<<<grid, MMD_THREADS, 0, stream>>>(
        b4, t4, wpart, nwslots, partial, n, m, gx, gy);

    final_kernel<<<1, 256, 0, stream>>>(
        bdesc, tdesc, g1, gb1, g2, gb2, bias, wpart, nwslots,
        partial, gx, gy, out);
}